// Round 11
// baseline (431.074 us; speedup 1.0000x reference)
//
#include <hip/hip_runtime.h>
#include <math.h>

#define NS   4
#define NB   256
#define NT   256
#define NH   128
#define NDW  64
#define NFH  48

// ===========================================================================
//  k_d1 : conv1 + f64 partial stats      (256 blocks = (s,chunk4) x 256 thr)
//  k_d3 : st1-finalize (redundant) + bn1+relu + conv2 + partial stats (256 b)
//  k_mat: collapsed operator (DPP-SKEWED layout) + (block 256) imid + Tg
//  k_ode: 4-wave K-SPLIT RK4 scan: wave w owns K-chunk w (16 coeffs);
//         per stage: 1 bperm + 16 fused DPP-fmac (even/odd ILP) +
//         double-buffered LDS combine with ONE barrier. 4 waves/SIMD.
//  k_gru: recon + fusion + GRU decoder
// ===========================================================================
__global__ __launch_bounds__(256) void k_d1(
    const float* __restrict__ x,
    const float* __restrict__ c1w, const float* __restrict__ c1b,
    float* __restrict__ tmpA, double* __restrict__ pp1)
{
    const int s     = blockIdx.x >> 6;
    const int chunk = blockIdx.x & 63;
    const int tid   = threadIdx.x;
    __shared__ double wred[4][2];

    float w[5];
#pragma unroll
    for (int k = 0; k < 5; ++k) w[k] = c1w[s*5 + k];
    const float cb = c1b[s];

    double ls = 0.0, lq = 0.0;
#pragma unroll
    for (int r = 0; r < 4; ++r) {
        const int bb = chunk*4 + r;
        const float* xb = x + bb*NT;
        float acc = cb;
#pragma unroll
        for (int k = 0; k < 5; ++k) {
            int tt = tid + k - 2;
            if (tt >= 0 && tt < NT) acc += xb[tt] * w[k];
        }
        tmpA[s*65536 + bb*NT + tid] = acc;
        ls += (double)acc; lq += (double)acc * (double)acc;
    }
#pragma unroll
    for (int off = 32; off > 0; off >>= 1) {
        ls += __shfl_xor(ls, off); lq += __shfl_xor(lq, off);
    }
    if ((tid & 63) == 0) { wred[tid>>6][0] = ls; wred[tid>>6][1] = lq; }
    __syncthreads();
    if (tid == 0) {
        pp1[(s*64 + chunk)*2 + 0] = wred[0][0]+wred[1][0]+wred[2][0]+wred[3][0];
        pp1[(s*64 + chunk)*2 + 1] = wred[0][1]+wred[1][1]+wred[2][1]+wred[3][1];
    }
}

__global__ __launch_bounds__(256) void k_d3(
    const float* __restrict__ tmpA, const double* __restrict__ pp1,
    const float* __restrict__ g1,  const float* __restrict__ b1,
    const float* __restrict__ c2w, const float* __restrict__ c2b,
    float* __restrict__ cv2, double* __restrict__ pp2)
{
    const int s     = blockIdx.x >> 6;
    const int chunk = blockIdx.x & 63;
    const int tid   = threadIdx.x;
    __shared__ float hsh[256];
    __shared__ double wred[4][2];

    double lsum = 0.0, lsq = 0.0;
    for (int q = 0; q < 64; ++q) {
        lsum += pp1[(s*64 + q)*2 + 0];
        lsq  += pp1[(s*64 + q)*2 + 1];
    }
    const double Nn = 65536.0;
    double mm = lsum / Nn;
    double vv = lsq / Nn - mm*mm;
    const float m1 = (float)mm, rs1 = (float)(1.0 / sqrt(vv + 1e-5));
    const float A1 = g1[s]*rs1, B1 = b1[s] - g1[s]*m1*rs1;

    float w[5];
#pragma unroll
    for (int k = 0; k < 5; ++k) w[k] = c2w[s*5 + k];
    const float cb = c2b[s];

    double ls = 0.0, lq = 0.0;
    for (int r = 0; r < 4; ++r) {
        const int bb = chunk*4 + r;
        float y = tmpA[s*65536 + bb*NT + tid];
        hsh[tid] = fmaxf(fmaf(A1, y, B1), 0.f);
        __syncthreads();
        float acc = cb;
#pragma unroll
        for (int k = 0; k < 5; ++k) {
            int tt = tid + k - 2;
            if (tt >= 0 && tt < NT) acc += hsh[tt] * w[k];
        }
        cv2[s*65536 + bb*NT + tid] = acc;
        ls += (double)acc; lq += (double)acc * (double)acc;
        __syncthreads();
    }
#pragma unroll
    for (int off = 32; off > 0; off >>= 1) {
        ls += __shfl_xor(ls, off); lq += __shfl_xor(lq, off);
    }
    if ((tid & 63) == 0) { wred[tid>>6][0] = ls; wred[tid>>6][1] = lq; }
    __syncthreads();
    if (tid == 0) {
        pp2[(s*64 + chunk)*2 + 0] = wred[0][0]+wred[1][0]+wred[2][0]+wred[3][0];
        pp2[(s*64 + chunk)*2 + 1] = wred[0][1]+wred[1][1]+wred[2][1]+wred[3][1];
    }
}

// ---------------------------------------------------------------------------
// k_mat: Mt stored in the DPP-skewed layout expected by k_ode:
//   Mt_slot[(s*64+c)*64 + (k&48) + (((c&15)-(k&15))&15)] = M[c][k]
// Block 256 computes the JAX argmin midpoint-index table + Tg.
// ---------------------------------------------------------------------------
__global__ __launch_bounds__(64) void k_mat(
    const float* __restrict__ dw1, const float* __restrict__ dw2,
    const float* __restrict__ db2, const float* __restrict__ tspan,
    float* __restrict__ Mt, float* __restrict__ bM,
    int* __restrict__ imid_g, float* __restrict__ Tg)
{
    if (blockIdx.x == 256) {
        __shared__ float ts[256];
        const int t = threadIdx.x;
        for (int e = t; e < 256; e += 64) ts[e] = tspan[e];
        __syncthreads();
        for (int i = t; i < 255; i += 64) {
            float t0 = ts[i], t1 = ts[i+1];
            float tm = t0 + (t1 - t0) * 0.5f;
            int best = 0; float bd = fabsf(ts[0] - tm);
            for (int j = 1; j < 256; ++j) {
                float d = fabsf(ts[j] - tm);
                if (d < bd) { bd = d; best = j; }
            }
            imid_g[i] = best;
        }
        if (t == 0) {
            float T = 0.f;
            for (int i = 0; i < 255; ++i) T += (ts[i+1] - ts[i]);
            Tg[0] = T;
        }
        return;
    }
    const int s = blockIdx.x >> 6;
    const int c = blockIdx.x & 63;
    const int k = threadIdx.x;
    __shared__ float col[128];

    col[k]      = dw1[(s*130 + k)*64 + c];
    col[k + 64] = dw1[(s*130 + 64 + k)*64 + c];
    __syncthreads();

    const float4* dp = (const float4*)(dw2 + (s*64 + k)*256);
    double acc = 0.0;
#pragma unroll 8
    for (int j4 = 0; j4 < 32; ++j4) {
        float4 dv = dp[j4];
        acc += (double)dv.x * (double)col[4*j4+0]
             + (double)dv.y * (double)col[4*j4+1]
             + (double)dv.z * (double)col[4*j4+2]
             + (double)dv.w * (double)col[4*j4+3];
    }
    const int slot = (k & 48) | (((c & 15) - (k & 15)) & 15);
    Mt[(s*64 + c)*64 + slot] = (float)acc;

    double pb = (double)db2[s*256 + k]      * (double)col[k]
              + (double)db2[s*256 + 64 + k] * (double)col[k + 64];
#pragma unroll
    for (int off = 32; off > 0; off >>= 1) pb += __shfl_xor(pb, off);
    if (k == 0) bM[s*64 + c] = (float)pb;
}

// ---------------------------------------------------------------------------
// k_ode v10: 1024 blocks x 256 threads (4 waves). Wave w owns K-chunk w:
// per stage 1 ds_bpermute + 16 fused DPP-fmac (even/odd accumulators for
// 2-way ILP; only 16 regs of skewed M per lane -> no AGPR pressure), then
// double-buffered LDS combine (1 ds_write_b32, ONE barrier, 1 ds_read_b128,
// fixed-order sum -> v bitwise-identical in all waves). All waves carry the
// a/S state redundantly; wave 0 stores. Mt skew table unchanged from R7.
// ---------------------------------------------------------------------------
__device__ __forceinline__ float rlf(float v, int l) {
    return __int_as_float(__builtin_amdgcn_readlane(__float_as_int(v), l));
}
__device__ __forceinline__ float pick4f(float r0, float r1, float r2, float r3, int i) {
    int l = i & 63, h = i >> 6;
    float a = (h & 2) ? ((h & 1) ? r3 : r2) : ((h & 1) ? r1 : r0);
    return rlf(a, l);
}
__device__ __forceinline__ float bperm(int addr, float v) {
    return __int_as_float(__builtin_amdgcn_ds_bpermute(addr, __float_as_int(v)));
}

#define KSTEP(pe, po) \
    asm("v_fmac_f32 %0, %1, %2 row_ror:" #pe " row_mask:0xf bank_mask:0xf" \
        : "+v"(d_e) : "v"(ug), "v"(McL[pe])); \
    asm("v_fmac_f32 %0, %1, %2 row_ror:" #po " row_mask:0xf bank_mask:0xf" \
        : "+v"(d_o) : "v"(ug), "v"(McL[po]));

// one RK4-stage dot: this wave's 16-wide partial + LDS combine (1 barrier)
#define DOT(uin, vout) { \
    float ug = bperm(A, (uin)); \
    float d_e = fmaf(ug, McL[0], seed); \
    float d_o; \
    asm("v_mul_f32 %0, %1, %2 row_ror:1 row_mask:0xf bank_mask:0xf" \
        : "=v"(d_o) : "v"(ug), "v"(McL[1])); \
    KSTEP(2,3)   KSTEP(4,5)   KSTEP(6,7)   KSTEP(8,9) \
    KSTEP(10,11) KSTEP(12,13) KSTEP(14,15) \
    pps[pb][l][w] = d_e + d_o; \
    __syncthreads(); \
    float4 pv = *(const float4*)&pps[pb][l][0]; \
    vout = (pv.x + pv.y) + (pv.z + pv.w); \
    pb ^= 1; }

__global__ __launch_bounds__(256, 4) void k_ode(
    const float* __restrict__ cv2, const double* __restrict__ pp2g,
    const float* __restrict__ g2,  const float* __restrict__ b2,
    const float* __restrict__ tspan, const int* __restrict__ imid_g,
    const float* __restrict__ Mt, const float* __restrict__ bM_g,
    const float* __restrict__ dw1, const float* __restrict__ db1,
    float* __restrict__ S_g)
{
    const int b   = blockIdx.x;
    const int s   = b >> 8;
    const int row = b & 255;
    const int tid = threadIdx.x;
    const int w   = tid >> 6;      // wave = K-chunk
    const int l   = tid & 63;      // lane = output column

    __shared__ __align__(16) float xls[256];
    __shared__ __align__(16) float xms[256];
    __shared__ __align__(16) float pps[2][64][4];

    // st2 finalize (redundant per block, deterministic)
    double lsum = 0.0, lsq = 0.0;
    for (int q = 0; q < 64; ++q) {
        lsum += pp2g[(s*64 + q)*2 + 0];
        lsq  += pp2g[(s*64 + q)*2 + 1];
    }
    const double Nn = 65536.0;
    double mmv = lsum / Nn;
    double vvv = lsq / Nn - mmv*mmv;
    const float m2 = (float)mmv, rs2 = (float)(1.0 / sqrt(vvv + 1e-5));
    const float bnA = g2[s]*rs2, bnB = b2[s] - g2[s]*m2*rs2;

    const float* __restrict__ xrow = cv2 + (s*NB + row)*NT;
    if (tid < 256) xls[tid] = fmaxf(fmaf(bnA, xrow[tid], bnB), 0.f);
    __syncthreads();
    if (tid < 255) xms[tid] = xls[imid_g[tid]];

    const float bMc = bM_g[s*64 + l];
    const float b1c = db1[s*64 + l];
    const float w1x = dw1[(s*130 + 128)*64 + l];
    const float w1t = dw1[(s*130 + 129)*64 + l];
    const float seed = (w == 0) ? bMc : 0.0f;

    // lane-distributed t_span (same in all waves)
    float tr0 = tspan[l],       tr1 = tspan[64 + l];
    float tr2 = tspan[128 + l], tr3 = tspan[192 + l];

    // this wave's 16 skewed-M coefficients (chunk w = slots 16w..16w+15)
    float McL[16];
    const float4* mp = (const float4*)(Mt + (s*64 + l)*64 + 16*w);
#pragma unroll
    for (int j = 0; j < 4; ++j) {
        float4 t = mp[j];
        McL[4*j+0] = t.x; McL[4*j+1] = t.y; McL[4*j+2] = t.z; McL[4*j+3] = t.w;
    }
#pragma unroll
    for (int j = 0; j < 16; ++j) asm volatile("" : "+v"(McL[j]));

    // bpermute byte-address: source lane 16w + (l&15)
    const int A = ((l & 15) << 2) + (w << 6);

    __syncthreads();   // xms ready

    float a = 0.f, S = 0.f;
    float t0  = rlf(tr0, 0);
    float t1  = rlf(tr0, 1);
    float xi  = xls[0], xmv = xms[0], x1v = xls[1];
    int   pb  = 0;

    for (int i = 0; i < 255; ++i) {
        float xin = 0.f, xmn = 0.f, x1n = 0.f, t1n = 0.f;
        if (i < 254) {
            xin = xls[i+1]; xmn = xms[i+1]; x1n = xls[i+2];
            t1n = pick4f(tr0, tr1, tr2, tr3, i + 2);
        }
        const float dt  = t1 - t0;
        const float tm  = t0 + dt * 0.5f;
        const float hdt = dt * 0.5f;
        const float c0  = b1c + xi*w1x  + t0*w1t;
        const float cm  = b1c + xmv*w1x + tm*w1t;
        const float c1  = b1c + x1v*w1x + t1*w1t;

        float u11 = fmaxf(a + c0, 0.f);
        float v1;  DOT(u11, v1)
        float u12 = fmaxf(fmaf(hdt, v1, a) + cm, 0.f);
        float v2;  DOT(u12, v2)
        float u13 = fmaxf(fmaf(hdt, v2, a) + cm, 0.f);
        float v3;  DOT(u13, v3)
        float u14 = fmaxf(fmaf(dt, v3, a) + c1, 0.f);
        float v4;  DOT(u14, v4)

        float d6 = dt * (1.0f / 6.0f);
        a += d6 * ((v1 + v4) + 2.f*(v2 + v3));
        S += d6 * ((u11 + u14) + 2.f*(u12 + u13));

        t0 = t1; t1 = t1n; xi = xin; xmv = xmn; x1v = x1n;
    }

    if (w == 0) S_g[(s*256 + row)*64 + l] = S;
}

// ---------------------------------------------------------------------------
// k_gru: fused recon (S -> means, exp(logvar)) + attention fusion + 48-step
// GRU decoder. One block per batch row (256 blocks x 384 threads).
// ---------------------------------------------------------------------------
__global__ __launch_bounds__(384, 1) void k_gru(
    const float* __restrict__ S_g, const float* __restrict__ dw2,
    const float* __restrict__ db2, const float* __restrict__ Tg,
    const float* __restrict__ a1w, const float* __restrict__ a1b,
    const float* __restrict__ a2w, const float* __restrict__ a2b,
    const float* __restrict__ wih, const float* __restrict__ whh,
    const float* __restrict__ bih, const float* __restrict__ bhh,
    const float* __restrict__ fcw, const float* __restrict__ fcb,
    const float* __restrict__ lvw, const float* __restrict__ lvb,
    const float* __restrict__ init_token, float* __restrict__ out)
{
    const int b   = blockIdx.x;
    const int tid = threadIdx.x;

    __shared__ __align__(16) float Ssh[4][64];
    __shared__ __align__(16) float msh[4][128];
    __shared__ __align__(16) float evs[4][128];
    __shared__ __align__(16) float hl[128];
    __shared__ float ghl[384];
    __shared__ float scoreL[4];
    __shared__ float unc_part[2][4];
    __shared__ float wgt[4];
    __shared__ float redL[2][2];
    __shared__ float tokL;

    if (tid < 256) {
        int s = tid >> 6, cc = tid & 63;
        Ssh[s][cc] = S_g[(s*256 + b)*64 + cc];
    }
    const float T = Tg[0];
    __syncthreads();

    for (int e = tid; e < 1024; e += 384) {
        int s = e >> 8, j = e & 255;
        float acc = T * db2[s*256 + j];
        const float4* s4 = (const float4*)Ssh[s];
#pragma unroll
        for (int k4 = 0; k4 < 16; ++k4) {
            float4 sv = s4[k4];
            acc += sv.x * dw2[(s*64 + 4*k4 + 0)*256 + j]
                 + sv.y * dw2[(s*64 + 4*k4 + 1)*256 + j]
                 + sv.z * dw2[(s*64 + 4*k4 + 2)*256 + j]
                 + sv.w * dw2[(s*64 + 4*k4 + 3)*256 + j];
        }
        if (j < 128) msh[s][j] = acc;
        else         evs[s][j - 128] = expf(acc);
    }
    __syncthreads();

    if (tid < 128) {
        int wv = tid >> 6;
#pragma unroll
        for (int s = 0; s < 4; ++s) {
            float v = evs[s][tid];
#pragma unroll
            for (int off = 32; off > 0; off >>= 1) v += __shfl_xor(v, off);
            if ((tid & 63) == 0) unc_part[wv][s] = v;
        }
    }
    if (tid < 128) {
        int s = tid >> 5, aq = tid & 31;
        float hd = a1b[aq];
#pragma unroll 4
        for (int i = 0; i < 128; ++i) hd += msh[s][i] * a1w[i*32 + aq];
        hd = fmaxf(hd, 0.f);
        float sc = hd * a2w[aq];
#pragma unroll
        for (int off = 16; off > 0; off >>= 1) sc += __shfl_xor(sc, off);
        if (aq == 0) scoreL[s] = sc + a2b[0];
    }
    __syncthreads();
    if (tid == 0) {
        float sv[4], mx = -1e30f;
#pragma unroll
        for (int s = 0; s < 4; ++s) {
            float u = (unc_part[0][s] + unc_part[1][s]) / 128.f;
            sv[s] = scoreL[s] / (u + 1e-6f);
            mx = fmaxf(mx, sv[s]);
        }
        float se = 0.f, ev[4];
#pragma unroll
        for (int s = 0; s < 4; ++s) { ev[s] = expf(sv[s] - mx); se += ev[s]; }
#pragma unroll
        for (int s = 0; s < 4; ++s) wgt[s] = ev[s] / se;
        tokL = init_token[0];
    }
    __syncthreads();
    if (tid < 128) {
        float f = 0.f;
#pragma unroll
        for (int s = 0; s < 4; ++s) f += wgt[s] * msh[s][tid];
        hl[tid] = f;
    }

    float4 whh4[32];
    const float4* wr = (const float4*)(whh + tid*128);
#pragma unroll
    for (int k = 0; k < 32; ++k) whh4[k] = wr[k];
    float bhhj = bhh[tid];
    float wih_r = 0.f, wih_z = 0.f, wih_n = 0.f;
    float bih_r = 0.f, bih_z = 0.f, bih_n = 0.f;
    float fcwi = 0.f, lvwi = 0.f;
    if (tid < 128) {
        wih_r = wih[tid]; wih_z = wih[128+tid]; wih_n = wih[256+tid];
        bih_r = bih[tid]; bih_z = bih[128+tid]; bih_n = bih[256+tid];
        fcwi  = fcw[tid]; lvwi  = lvw[tid];
    }
    const float fcbv = fcb[0], lvbv = lvb[0];
    __syncthreads();

    for (int t = 0; t < NFH; ++t) {
        float g0 = 0.f, g1 = 0.f, g2 = 0.f, g3 = 0.f;
        const float4* h4 = (const float4*)hl;
#pragma unroll
        for (int k = 0; k < 32; ++k) {
            float4 hv = h4[k];
            float4 wvv = whh4[k];
            g0 += hv.x * wvv.x; g1 += hv.y * wvv.y;
            g2 += hv.z * wvv.z; g3 += hv.w * wvv.w;
        }
        ghl[tid] = ((g0 + g1) + (g2 + g3)) + bhhj;
        __syncthreads();

        if (tid < 128) {
            float tok = tokL;
            float r  = 1.f / (1.f + expf(-(tok*wih_r + bih_r + ghl[tid])));
            float zz = 1.f / (1.f + expf(-(tok*wih_z + bih_z + ghl[128+tid])));
            float n  = tanhf(tok*wih_n + bih_n + r * ghl[256+tid]);
            float hn = (1.f - zz) * n + zz * hl[tid];
            hl[tid] = hn;
            float pg = hn * fcwi, pl = hn * lvwi;
#pragma unroll
            for (int off = 32; off > 0; off >>= 1) {
                pg += __shfl_xor(pg, off);
                pl += __shfl_xor(pl, off);
            }
            int wvx = tid >> 6;
            if ((tid & 63) == 0) { redL[wvx][0] = pg; redL[wvx][1] = pl; }
        }
        __syncthreads();
        if (tid == 0) {
            float pr = redL[0][0] + redL[1][0] + fcbv;
            float pv = redL[0][1] + redL[1][1] + lvbv;
            out[b*NFH + t] = pr;
            out[NB*NFH + b*NFH + t] = pv;
            tokL = pr;
        }
        __syncthreads();
    }
}

// ---------------------------------------------------------------------------
extern "C" void kernel_launch(void* const* d_in, const int* in_sizes, int n_in,
                              void* d_out, int out_size, void* d_ws, size_t ws_size,
                              hipStream_t stream)
{
    const float* x      = (const float*)d_in[0];
    const float* tspan  = (const float*)d_in[1];
    const float* c1w    = (const float*)d_in[2];
    const float* c1b    = (const float*)d_in[3];
    const float* bn1g   = (const float*)d_in[4];
    const float* bn1b   = (const float*)d_in[5];
    const float* c2w    = (const float*)d_in[6];
    const float* c2b    = (const float*)d_in[7];
    const float* bn2g   = (const float*)d_in[8];
    const float* bn2b   = (const float*)d_in[9];
    const float* dw1    = (const float*)d_in[10];
    const float* db1    = (const float*)d_in[11];
    const float* dw2    = (const float*)d_in[12];
    const float* db2    = (const float*)d_in[13];
    const float* a1w    = (const float*)d_in[14];
    const float* a1b    = (const float*)d_in[15];
    const float* a2w    = (const float*)d_in[16];
    const float* a2b    = (const float*)d_in[17];
    const float* wih    = (const float*)d_in[18];
    const float* whh    = (const float*)d_in[19];
    const float* bih    = (const float*)d_in[20];
    const float* bhh    = (const float*)d_in[21];
    const float* fcw    = (const float*)d_in[22];
    const float* fcb    = (const float*)d_in[23];
    const float* lvw    = (const float*)d_in[24];
    const float* lvb    = (const float*)d_in[25];
    const float* itok   = (const float*)d_in[26];

    float* ws    = (float*)d_ws;
    float*  cv2  = ws;                        // 262144
    float*  tmpA = ws + 262144;               // 262144
    float*  S_g  = ws + 524288;               // 65536
    float*  Mt   = ws + 589824;               // 16384 (DPP-skewed)
    float*  bMg  = ws + 606208;               // 256
    float*  Tg   = ws + 606464;               // 1 (padded)
    int*    imid = (int*)(ws + 606720);       // 256 ints
    double* pp1  = (double*)(ws + 606976);    // 512 doubles
    double* pp2  = (double*)(ws + 608000);    // 512 doubles

    k_d1<<<256, 256, 0, stream>>>(x, c1w, c1b, tmpA, pp1);
    k_mat<<<257, 64, 0, stream>>>(dw1, dw2, db2, tspan, Mt, bMg, imid, Tg);
    k_d3<<<256, 256, 0, stream>>>(tmpA, pp1, bn1g, bn1b, c2w, c2b, cv2, pp2);
    k_ode<<<1024, 256, 0, stream>>>(cv2, pp2, bn2g, bn2b, tspan, imid,
                                    Mt, bMg, dw1, db1, S_g);
    k_gru<<<256, 384, 0, stream>>>(S_g, dw2, db2, Tg, a1w, a1b, a2w, a2b,
                                   wih, whh, bih, bhh, fcw, fcb, lvw, lvb,
                                   itok, (float*)d_out);
}

// Round 12
// 342.084 us; speedup vs baseline: 1.2601x; 1.2601x over previous
//
#include <hip/hip_runtime.h>
#include <math.h>

#define NS   4
#define NB   256
#define NT   256
#define NH   128
#define NDW  64
#define NFH  48

// ===========================================================================
//  k_d1 : conv1 + f64 partial stats      (256 blocks = (s,chunk4) x 256 thr)
//  k_d3 : st1-finalize (redundant) + bn1+relu + conv2 + partial stats (256 b)
//  k_mat: collapsed operator (DPP-SKEWED layout) + (block 256) imid + Tg
//  k_ode: st2-finalize + RK4 scan; matvec = 4 ds_bpermute + 64 fused
//         v_fmac_f32+row_ror DPP (inline asm) — verified best (R7, 235 us)
//  k_gru: recon + fusion + GRU decoder
// ===========================================================================
__global__ __launch_bounds__(256) void k_d1(
    const float* __restrict__ x,
    const float* __restrict__ c1w, const float* __restrict__ c1b,
    float* __restrict__ tmpA, double* __restrict__ pp1)
{
    const int s     = blockIdx.x >> 6;
    const int chunk = blockIdx.x & 63;
    const int tid   = threadIdx.x;
    __shared__ double wred[4][2];

    float w[5];
#pragma unroll
    for (int k = 0; k < 5; ++k) w[k] = c1w[s*5 + k];
    const float cb = c1b[s];

    double ls = 0.0, lq = 0.0;
#pragma unroll
    for (int r = 0; r < 4; ++r) {
        const int bb = chunk*4 + r;
        const float* xb = x + bb*NT;
        float acc = cb;
#pragma unroll
        for (int k = 0; k < 5; ++k) {
            int tt = tid + k - 2;
            if (tt >= 0 && tt < NT) acc += xb[tt] * w[k];
        }
        tmpA[s*65536 + bb*NT + tid] = acc;
        ls += (double)acc; lq += (double)acc * (double)acc;
    }
#pragma unroll
    for (int off = 32; off > 0; off >>= 1) {
        ls += __shfl_xor(ls, off); lq += __shfl_xor(lq, off);
    }
    if ((tid & 63) == 0) { wred[tid>>6][0] = ls; wred[tid>>6][1] = lq; }
    __syncthreads();
    if (tid == 0) {
        pp1[(s*64 + chunk)*2 + 0] = wred[0][0]+wred[1][0]+wred[2][0]+wred[3][0];
        pp1[(s*64 + chunk)*2 + 1] = wred[0][1]+wred[1][1]+wred[2][1]+wred[3][1];
    }
}

__global__ __launch_bounds__(256) void k_d3(
    const float* __restrict__ tmpA, const double* __restrict__ pp1,
    const float* __restrict__ g1,  const float* __restrict__ b1,
    const float* __restrict__ c2w, const float* __restrict__ c2b,
    float* __restrict__ cv2, double* __restrict__ pp2)
{
    const int s     = blockIdx.x >> 6;
    const int chunk = blockIdx.x & 63;
    const int tid   = threadIdx.x;
    __shared__ float hsh[256];
    __shared__ double wred[4][2];

    double lsum = 0.0, lsq = 0.0;
    for (int q = 0; q < 64; ++q) {
        lsum += pp1[(s*64 + q)*2 + 0];
        lsq  += pp1[(s*64 + q)*2 + 1];
    }
    const double Nn = 65536.0;
    double mm = lsum / Nn;
    double vv = lsq / Nn - mm*mm;
    const float m1 = (float)mm, rs1 = (float)(1.0 / sqrt(vv + 1e-5));
    const float A1 = g1[s]*rs1, B1 = b1[s] - g1[s]*m1*rs1;

    float w[5];
#pragma unroll
    for (int k = 0; k < 5; ++k) w[k] = c2w[s*5 + k];
    const float cb = c2b[s];

    double ls = 0.0, lq = 0.0;
    for (int r = 0; r < 4; ++r) {
        const int bb = chunk*4 + r;
        float y = tmpA[s*65536 + bb*NT + tid];
        hsh[tid] = fmaxf(fmaf(A1, y, B1), 0.f);
        __syncthreads();
        float acc = cb;
#pragma unroll
        for (int k = 0; k < 5; ++k) {
            int tt = tid + k - 2;
            if (tt >= 0 && tt < NT) acc += hsh[tt] * w[k];
        }
        cv2[s*65536 + bb*NT + tid] = acc;
        ls += (double)acc; lq += (double)acc * (double)acc;
        __syncthreads();
    }
#pragma unroll
    for (int off = 32; off > 0; off >>= 1) {
        ls += __shfl_xor(ls, off); lq += __shfl_xor(lq, off);
    }
    if ((tid & 63) == 0) { wred[tid>>6][0] = ls; wred[tid>>6][1] = lq; }
    __syncthreads();
    if (tid == 0) {
        pp2[(s*64 + chunk)*2 + 0] = wred[0][0]+wred[1][0]+wred[2][0]+wred[3][0];
        pp2[(s*64 + chunk)*2 + 1] = wred[0][1]+wred[1][1]+wred[2][1]+wred[3][1];
    }
}

// ---------------------------------------------------------------------------
// k_mat: Mt stored in the DPP-skewed layout expected by k_ode:
//   Mt_slot[(s*64+c)*64 + (k&48) + (((c&15)-(k&15))&15)] = M[c][k]
// Block 256 computes the JAX argmin midpoint-index table + Tg.
// ---------------------------------------------------------------------------
__global__ __launch_bounds__(64) void k_mat(
    const float* __restrict__ dw1, const float* __restrict__ dw2,
    const float* __restrict__ db2, const float* __restrict__ tspan,
    float* __restrict__ Mt, float* __restrict__ bM,
    int* __restrict__ imid_g, float* __restrict__ Tg)
{
    if (blockIdx.x == 256) {
        __shared__ float ts[256];
        const int t = threadIdx.x;
        for (int e = t; e < 256; e += 64) ts[e] = tspan[e];
        __syncthreads();
        for (int i = t; i < 255; i += 64) {
            float t0 = ts[i], t1 = ts[i+1];
            float tm = t0 + (t1 - t0) * 0.5f;
            int best = 0; float bd = fabsf(ts[0] - tm);
            for (int j = 1; j < 256; ++j) {
                float d = fabsf(ts[j] - tm);
                if (d < bd) { bd = d; best = j; }
            }
            imid_g[i] = best;
        }
        if (t == 0) {
            float T = 0.f;
            for (int i = 0; i < 255; ++i) T += (ts[i+1] - ts[i]);
            Tg[0] = T;
        }
        return;
    }
    const int s = blockIdx.x >> 6;
    const int c = blockIdx.x & 63;
    const int k = threadIdx.x;
    __shared__ float col[128];

    col[k]      = dw1[(s*130 + k)*64 + c];
    col[k + 64] = dw1[(s*130 + 64 + k)*64 + c];
    __syncthreads();

    const float4* dp = (const float4*)(dw2 + (s*64 + k)*256);
    double acc = 0.0;
#pragma unroll 8
    for (int j4 = 0; j4 < 32; ++j4) {
        float4 dv = dp[j4];
        acc += (double)dv.x * (double)col[4*j4+0]
             + (double)dv.y * (double)col[4*j4+1]
             + (double)dv.z * (double)col[4*j4+2]
             + (double)dv.w * (double)col[4*j4+3];
    }
    const int slot = (k & 48) | (((c & 15) - (k & 15)) & 15);
    Mt[(s*64 + c)*64 + slot] = (float)acc;

    double pb = (double)db2[s*256 + k]      * (double)col[k]
              + (double)db2[s*256 + 64 + k] * (double)col[k + 64];
#pragma unroll
    for (int off = 32; off > 0; off >>= 1) pb += __shfl_xor(pb, off);
    if (k == 0) bM[s*64 + c] = (float)pb;
}

// ---------------------------------------------------------------------------
// k_ode (R7, verified best): RK4 scan, collapsed 64-dim space. 1024 blocks
// x 64 threads. dot64: 4 ds_bpermute build u_g = u1[16g + (l&15)], then 16
// steps x 4 chunks of v_fmac_f32 with the rotation FUSED as a row_ror:p DPP
// modifier on src0 (inline asm) — rotation costs zero extra instructions.
// Accumulation order: (d0+d1)+(d2+d3), bMc seeded in d0, p ascending.
// ---------------------------------------------------------------------------
__device__ __forceinline__ float bperm(int addr, float v) {
    return __int_as_float(__builtin_amdgcn_ds_bpermute(addr, __float_as_int(v)));
}

#define FSTEP(p) \
    asm("v_fmac_f32 %0, %1, %2 row_ror:" #p " row_mask:0xf bank_mask:0xf" \
        : "+v"(d0) : "v"(u0), "v"(Mc[p])); \
    asm("v_fmac_f32 %0, %1, %2 row_ror:" #p " row_mask:0xf bank_mask:0xf" \
        : "+v"(d1) : "v"(u1), "v"(Mc[16+(p)])); \
    asm("v_fmac_f32 %0, %1, %2 row_ror:" #p " row_mask:0xf bank_mask:0xf" \
        : "+v"(d2) : "v"(u2), "v"(Mc[32+(p)])); \
    asm("v_fmac_f32 %0, %1, %2 row_ror:" #p " row_mask:0xf bank_mask:0xf" \
        : "+v"(d3) : "v"(u3), "v"(Mc[48+(p)]));

__device__ __forceinline__ float dotFDPP(float u, const float* __restrict__ Mc,
                                         float bMc, int A0, int A1, int A2, int A3)
{
    float u0 = bperm(A0, u), u1 = bperm(A1, u);
    float u2 = bperm(A2, u), u3 = bperm(A3, u);
    float d0 = fmaf(u0, Mc[0], bMc);
    float d1 = u1 * Mc[16];
    float d2 = u2 * Mc[32];
    float d3 = u3 * Mc[48];
    FSTEP(1)  FSTEP(2)  FSTEP(3)  FSTEP(4)  FSTEP(5)  FSTEP(6)  FSTEP(7)
    FSTEP(8)  FSTEP(9)  FSTEP(10) FSTEP(11) FSTEP(12) FSTEP(13) FSTEP(14)
    FSTEP(15)
    return (d0 + d1) + (d2 + d3);
}

__global__ __attribute__((amdgpu_waves_per_eu(1, 1)))
__launch_bounds__(64) void k_ode(
    const float* __restrict__ cv2, const double* __restrict__ pp2,
    const float* __restrict__ g2,  const float* __restrict__ b2,
    const float* __restrict__ tspan, const int* __restrict__ imid_g,
    const float* __restrict__ Mt, const float* __restrict__ bM_g,
    const float* __restrict__ dw1, const float* __restrict__ db1,
    float* __restrict__ S_g)
{
    const int b   = blockIdx.x;
    const int s   = b >> 8;
    const int row = b & 255;
    const int l   = threadIdx.x;

    __shared__ __align__(16) float xls[256];
    __shared__ __align__(16) float xms[256];

    // st2 finalize (redundant per block, deterministic)
    double lsum = 0.0, lsq = 0.0;
    for (int q = 0; q < 64; ++q) {
        lsum += pp2[(s*64 + q)*2 + 0];
        lsq  += pp2[(s*64 + q)*2 + 1];
    }
    const double Nn = 65536.0;
    double mm = lsum / Nn;
    double vv = lsq / Nn - mm*mm;
    const float m2 = (float)mm, rs2 = (float)(1.0 / sqrt(vv + 1e-5));
    const float bnA = g2[s]*rs2, bnB = b2[s] - g2[s]*m2*rs2;

    const float* __restrict__ xrow = cv2 + (s*NB + row)*NT;
#pragma unroll
    for (int q = 0; q < 4; ++q)
        xls[64*q + l] = fmaxf(fmaf(bnA, xrow[64*q + l], bnB), 0.f);
    __syncthreads();
#pragma unroll
    for (int q = 0; q < 4; ++q) {
        int idx = 64*q + l;
        if (idx < 255) xms[idx] = xls[imid_g[idx]];
    }
    __syncthreads();

    const float bMc = bM_g[s*64 + l];
    const float b1c = db1[s*64 + l];
    const float w1x = dw1[(s*130 + 128)*64 + l];
    const float w1t = dw1[(s*130 + 129)*64 + l];

    float Mc[64];
    const float4* mp = (const float4*)(Mt + (s*64 + l)*64);
#pragma unroll
    for (int j = 0; j < 16; ++j) {
        float4 t = mp[j];
        Mc[4*j+0] = t.x; Mc[4*j+1] = t.y; Mc[4*j+2] = t.z; Mc[4*j+3] = t.w;
    }
#pragma unroll
    for (int j = 0; j < 64; ++j) asm volatile("" : "+v"(Mc[j]));

    // bpermute byte-addresses: source lane 16g + (l&15)
    const int lm = (l & 15) << 2;
    const int A0 = lm, A1 = lm + 64, A2 = lm + 128, A3 = lm + 192;

    float a = 0.f;
    float S = 0.f;

    for (int i = 0; i < 255; ++i) {
        const float t0 = tspan[i];
        const float t1 = tspan[i+1];
        const float dt = t1 - t0;
        const float tm = t0 + dt * 0.5f;
        const float hdt = dt * 0.5f;
        const float xi  = xls[i];
        const float x1v = xls[i+1];
        const float xm  = xms[i];

        float u11 = fmaxf(a + b1c + xi*w1x + t0*w1t, 0.f);
        float v1  = dotFDPP(u11, Mc, bMc, A0, A1, A2, A3);
        float u12 = fmaxf(fmaf(hdt, v1, a) + b1c + xm*w1x + tm*w1t, 0.f);
        float v2  = dotFDPP(u12, Mc, bMc, A0, A1, A2, A3);
        float u13 = fmaxf(fmaf(hdt, v2, a) + b1c + xm*w1x + tm*w1t, 0.f);
        float v3  = dotFDPP(u13, Mc, bMc, A0, A1, A2, A3);
        float u14 = fmaxf(fmaf(dt, v3, a) + b1c + x1v*w1x + t1*w1t, 0.f);
        float v4  = dotFDPP(u14, Mc, bMc, A0, A1, A2, A3);

        float d6 = dt * (1.0f / 6.0f);
        a += d6 * ((v1 + v4) + 2.f*(v2 + v3));
        S += d6 * ((u11 + u14) + 2.f*(u12 + u13));
    }

    S_g[(s*256 + row)*64 + l] = S;
}

// ---------------------------------------------------------------------------
// k_gru: fused recon (S -> means, exp(logvar)) + attention fusion + 48-step
// GRU decoder. One block per batch row (256 blocks x 384 threads).
// ---------------------------------------------------------------------------
__global__ __launch_bounds__(384, 1) void k_gru(
    const float* __restrict__ S_g, const float* __restrict__ dw2,
    const float* __restrict__ db2, const float* __restrict__ Tg,
    const float* __restrict__ a1w, const float* __restrict__ a1b,
    const float* __restrict__ a2w, const float* __restrict__ a2b,
    const float* __restrict__ wih, const float* __restrict__ whh,
    const float* __restrict__ bih, const float* __restrict__ bhh,
    const float* __restrict__ fcw, const float* __restrict__ fcb,
    const float* __restrict__ lvw, const float* __restrict__ lvb,
    const float* __restrict__ init_token, float* __restrict__ out)
{
    const int b   = blockIdx.x;
    const int tid = threadIdx.x;

    __shared__ __align__(16) float Ssh[4][64];
    __shared__ __align__(16) float msh[4][128];
    __shared__ __align__(16) float evs[4][128];
    __shared__ __align__(16) float hl[128];
    __shared__ float ghl[384];
    __shared__ float scoreL[4];
    __shared__ float unc_part[2][4];
    __shared__ float wgt[4];
    __shared__ float redL[2][2];
    __shared__ float tokL;

    if (tid < 256) {
        int s = tid >> 6, cc = tid & 63;
        Ssh[s][cc] = S_g[(s*256 + b)*64 + cc];
    }
    const float T = Tg[0];
    __syncthreads();

    for (int e = tid; e < 1024; e += 384) {
        int s = e >> 8, j = e & 255;
        float acc = T * db2[s*256 + j];
        const float4* s4 = (const float4*)Ssh[s];
#pragma unroll
        for (int k4 = 0; k4 < 16; ++k4) {
            float4 sv = s4[k4];
            acc += sv.x * dw2[(s*64 + 4*k4 + 0)*256 + j]
                 + sv.y * dw2[(s*64 + 4*k4 + 1)*256 + j]
                 + sv.z * dw2[(s*64 + 4*k4 + 2)*256 + j]
                 + sv.w * dw2[(s*64 + 4*k4 + 3)*256 + j];
        }
        if (j < 128) msh[s][j] = acc;
        else         evs[s][j - 128] = expf(acc);
    }
    __syncthreads();

    if (tid < 128) {
        int wv = tid >> 6;
#pragma unroll
        for (int s = 0; s < 4; ++s) {
            float v = evs[s][tid];
#pragma unroll
            for (int off = 32; off > 0; off >>= 1) v += __shfl_xor(v, off);
            if ((tid & 63) == 0) unc_part[wv][s] = v;
        }
    }
    if (tid < 128) {
        int s = tid >> 5, aq = tid & 31;
        float hd = a1b[aq];
#pragma unroll 4
        for (int i = 0; i < 128; ++i) hd += msh[s][i] * a1w[i*32 + aq];
        hd = fmaxf(hd, 0.f);
        float sc = hd * a2w[aq];
#pragma unroll
        for (int off = 16; off > 0; off >>= 1) sc += __shfl_xor(sc, off);
        if (aq == 0) scoreL[s] = sc + a2b[0];
    }
    __syncthreads();
    if (tid == 0) {
        float sv[4], mx = -1e30f;
#pragma unroll
        for (int s = 0; s < 4; ++s) {
            float u = (unc_part[0][s] + unc_part[1][s]) / 128.f;
            sv[s] = scoreL[s] / (u + 1e-6f);
            mx = fmaxf(mx, sv[s]);
        }
        float se = 0.f, ev[4];
#pragma unroll
        for (int s = 0; s < 4; ++s) { ev[s] = expf(sv[s] - mx); se += ev[s]; }
#pragma unroll
        for (int s = 0; s < 4; ++s) wgt[s] = ev[s] / se;
        tokL = init_token[0];
    }
    __syncthreads();
    if (tid < 128) {
        float f = 0.f;
#pragma unroll
        for (int s = 0; s < 4; ++s) f += wgt[s] * msh[s][tid];
        hl[tid] = f;
    }

    float4 whh4[32];
    const float4* wr = (const float4*)(whh + tid*128);
#pragma unroll
    for (int k = 0; k < 32; ++k) whh4[k] = wr[k];
    float bhhj = bhh[tid];
    float wih_r = 0.f, wih_z = 0.f, wih_n = 0.f;
    float bih_r = 0.f, bih_z = 0.f, bih_n = 0.f;
    float fcwi = 0.f, lvwi = 0.f;
    if (tid < 128) {
        wih_r = wih[tid]; wih_z = wih[128+tid]; wih_n = wih[256+tid];
        bih_r = bih[tid]; bih_z = bih[128+tid]; bih_n = bih[256+tid];
        fcwi  = fcw[tid]; lvwi  = lvw[tid];
    }
    const float fcbv = fcb[0], lvbv = lvb[0];
    __syncthreads();

    for (int t = 0; t < NFH; ++t) {
        float g0 = 0.f, g1 = 0.f, g2 = 0.f, g3 = 0.f;
        const float4* h4 = (const float4*)hl;
#pragma unroll
        for (int k = 0; k < 32; ++k) {
            float4 hv = h4[k];
            float4 wvv = whh4[k];
            g0 += hv.x * wvv.x; g1 += hv.y * wvv.y;
            g2 += hv.z * wvv.z; g3 += hv.w * wvv.w;
        }
        ghl[tid] = ((g0 + g1) + (g2 + g3)) + bhhj;
        __syncthreads();

        if (tid < 128) {
            float tok = tokL;
            float r  = 1.f / (1.f + expf(-(tok*wih_r + bih_r + ghl[tid])));
            float zz = 1.f / (1.f + expf(-(tok*wih_z + bih_z + ghl[128+tid])));
            float n  = tanhf(tok*wih_n + bih_n + r * ghl[256+tid]);
            float hn = (1.f - zz) * n + zz * hl[tid];
            hl[tid] = hn;
            float pg = hn * fcwi, pl = hn * lvwi;
#pragma unroll
            for (int off = 32; off > 0; off >>= 1) {
                pg += __shfl_xor(pg, off);
                pl += __shfl_xor(pl, off);
            }
            int wvx = tid >> 6;
            if ((tid & 63) == 0) { redL[wvx][0] = pg; redL[wvx][1] = pl; }
        }
        __syncthreads();
        if (tid == 0) {
            float pr = redL[0][0] + redL[1][0] + fcbv;
            float pv = redL[0][1] + redL[1][1] + lvbv;
            out[b*NFH + t] = pr;
            out[NB*NFH + b*NFH + t] = pv;
            tokL = pr;
        }
        __syncthreads();
    }
}

// ---------------------------------------------------------------------------
extern "C" void kernel_launch(void* const* d_in, const int* in_sizes, int n_in,
                              void* d_out, int out_size, void* d_ws, size_t ws_size,
                              hipStream_t stream)
{
    const float* x      = (const float*)d_in[0];
    const float* tspan  = (const float*)d_in[1];
    const float* c1w    = (const float*)d_in[2];
    const float* c1b    = (const float*)d_in[3];
    const float* bn1g   = (const float*)d_in[4];
    const float* bn1b   = (const float*)d_in[5];
    const float* c2w    = (const float*)d_in[6];
    const float* c2b    = (const float*)d_in[7];
    const float* bn2g   = (const float*)d_in[8];
    const float* bn2b   = (const float*)d_in[9];
    const float* dw1    = (const float*)d_in[10];
    const float* db1    = (const float*)d_in[11];
    const float* dw2    = (const float*)d_in[12];
    const float* db2    = (const float*)d_in[13];
    const float* a1w    = (const float*)d_in[14];
    const float* a1b    = (const float*)d_in[15];
    const float* a2w    = (const float*)d_in[16];
    const float* a2b    = (const float*)d_in[17];
    const float* wih    = (const float*)d_in[18];
    const float* whh    = (const float*)d_in[19];
    const float* bih    = (const float*)d_in[20];
    const float* bhh    = (const float*)d_in[21];
    const float* fcw    = (const float*)d_in[22];
    const float* fcb    = (const float*)d_in[23];
    const float* lvw    = (const float*)d_in[24];
    const float* lvb    = (const float*)d_in[25];
    const float* itok   = (const float*)d_in[26];

    float* ws    = (float*)d_ws;
    float*  cv2  = ws;                        // 262144
    float*  tmpA = ws + 262144;               // 262144
    float*  S_g  = ws + 524288;               // 65536
    float*  Mt   = ws + 589824;               // 16384 (DPP-skewed)
    float*  bMg  = ws + 606208;               // 256
    float*  Tg   = ws + 606464;               // 1 (padded)
    int*    imid = (int*)(ws + 606720);       // 256 ints
    double* pp1  = (double*)(ws + 606976);    // 512 doubles
    double* pp2  = (double*)(ws + 608000);    // 512 doubles

    k_d1<<<256, 256, 0, stream>>>(x, c1w, c1b, tmpA, pp1);
    k_mat<<<257, 64, 0, stream>>>(dw1, dw2, db2, tspan, Mt, bMg, imid, Tg);
    k_d3<<<256, 256, 0, stream>>>(tmpA, pp1, bn1g, bn1b, c2w, c2b, cv2, pp2);
    k_ode<<<1024, 64, 0, stream>>>(cv2, pp2, bn2g, bn2b, tspan, imid,
                                   Mt, bMg, dw1, db1, S_g);
    k_gru<<<256, 384, 0, stream>>>(S_g, dw2, db2, Tg, a1w, a1b, a2w, a2b,
                                   wih, whh, bih, bhh, fcw, fcb, lvw, lvb,
                                   itok, (float*)d_out);
}